// Round 6
// baseline (154.984 us; speedup 1.0000x reference)
//
#include <hip/hip_runtime.h>

// RT-DETR Hungarian matcher cost matrix.
// B=32, Q=300, C=80, T=100. Out: (B*Q) x (B*T) = 9600 x 3200 fp32 = 122.9 MB.
// cost = 5*L1 + 2*focal_class - 2*GIoU
//
// R5 (= R4 with the nontemporal-store type fixed):
//  - RCHUNK 32 -> 8: 4800 blocks (18.75/CU) -> kills tail quantization and
//    lets block rounds pipeline across fill/barrier phases.
//  - nontemporal stores via clang ext_vector float4 (HIP_vector_type float4
//    is a class -> rejected by __builtin_nontemporal_store).
//  - launch_bounds(256,4): <=128 VGPR, 4 blocks/CU co-resident.
// Class table: s_cc = 2*(pos-neg) + 2 (focal cost pre-scaled, +2 folds the
// giou constant:  -2*giou = 2 - 2*iou - 2*uni/enc).

typedef float vfloat4 __attribute__((ext_vector_type(4)));

constexpr int BB = 32, QQ = 300, CN = 80, TT = 100;
constexpr int NQ = BB * QQ;       // 9600 query rows
constexpr int NT = BB * TT;       // 3200 targets
constexpr int JG = NT / 4;        // 800 groups of 4 targets
constexpr int RCHUNK = 8;         // query rows per block (9600 = 1200 * 8)
constexpr int STRIPES = (JG + 255) / 256;   // 4 column stripes
constexpr int CCN = RCHUNK * CN;  // 640 class-cost entries per block

__global__ __launch_bounds__(256, 4) void fused_kernel(
    const float*  __restrict__ logits,        // NQ*80
    const float4* __restrict__ pred_boxes,    // NQ   (cx,cy,w,h)
    const int*    __restrict__ labels,        // NT
    const float4* __restrict__ target_boxes,  // NT   (cx,cy,w,h)
    vfloat4*      __restrict__ out)           // NQ * JG
{
  const int tid  = threadIdx.x;
  const int jg   = blockIdx.x * 256 + tid;    // target group [0, 800)
  const int row0 = blockIdx.y * RCHUNK;

  __shared__ float  s_cc[CCN];                // [8 rows][80 classes], 2.5 KB
  __shared__ float4 s_pred[RCHUNK];

  // ---- fill phase: focal class cost (+2 giou-constant bias) ----
  const float* lgbase = logits + (size_t)row0 * CN;
  for (int e = tid; e < CCN; e += 256) {
    float x = lgbase[e];
    float p = 1.0f / (1.0f + expf(-x));
    float neg = 0.75f * p * p * (-logf(1.0f - p + 1e-8f));
    float pos = 0.25f * (1.0f - p) * (1.0f - p) * (-logf(p + 1e-8f));
    s_cc[e] = 2.0f * (pos - neg) + 2.0f;      // C_CLASS=2 pre-scaled, +2 bias
  }
  if (tid < RCHUNK) s_pred[tid] = pred_boxes[row0 + tid];
  __syncthreads();
  if (jg >= JG) return;

  // ---- per-thread target state: 4 targets, pinned in registers ----
  float tcx[4], tcy[4], tw[4], th[4];
  float tx0[4], ty0[4], tx1[4], ty1[4], ta[4];
  const float* ccbase[4];                     // s_cc + label; row via imm offset
#pragma unroll
  for (int k = 0; k < 4; ++k) {
    float4 t = target_boxes[jg * 4 + k];
    tcx[k] = t.x; tcy[k] = t.y; tw[k] = t.z; th[k] = t.w;
    tx0[k] = t.x - 0.5f * t.z;  ty0[k] = t.y - 0.5f * t.w;
    tx1[k] = t.x + 0.5f * t.z;  ty1[k] = t.y + 0.5f * t.w;
    ta[k]  = (tx1[k] - tx0[k]) * (ty1[k] - ty0[k]);
    ccbase[k] = s_cc + labels[jg * 4 + k];
  }

  vfloat4* outp = out + (size_t)row0 * JG + jg;

#pragma unroll
  for (int r = 0; r < RCHUNK; ++r) {
    float4 p = s_pred[r];                      // wave-uniform broadcast
    float px0 = p.x - 0.5f * p.z, py0 = p.y - 0.5f * p.w;
    float px1 = p.x + 0.5f * p.z, py1 = p.y + 0.5f * p.w;
    float pa  = (px1 - px0) * (py1 - py0);

    vfloat4 res;
#pragma unroll
    for (int k = 0; k < 4; ++k) {
      // L1 in center format
      float l1 = fabsf(p.x - tcx[k]) + fabsf(p.y - tcy[k]) +
                 fabsf(p.z - tw[k])  + fabsf(p.w - th[k]);
      // intersection
      float ltx = fmaxf(px0, tx0[k]), lty = fmaxf(py0, ty0[k]);
      float rbx = fminf(px1, tx1[k]), rby = fminf(py1, ty1[k]);
      float iw = fmaxf(rbx - ltx, 0.0f), ih = fmaxf(rby - lty, 0.0f);
      float inter = iw * ih;
      float uni = pa + ta[k] - inter;
      // enclosing box (max-min >= 0 here, no clamp needed)
      float ex0 = fminf(px0, tx0[k]), ey0 = fminf(py0, ty0[k]);
      float ex1 = fmaxf(px1, tx1[k]), ey1 = fmaxf(py1, ty1[k]);
      float enc = (ex1 - ex0) * (ey1 - ey0);
      // -2*giou = 2 - 2*iou - 2*uni/enc; +2 lives in the class table
      float iou   = inter * __builtin_amdgcn_rcpf(uni);
      float une   = uni   * __builtin_amdgcn_rcpf(enc);
      float cls   = ccbase[k][r * CN];         // ds_read_b32, imm offset
      float acc   = fmaf(5.0f, l1, cls);
      acc         = fmaf(-2.0f, iou, acc);
      res[k]      = fmaf(-2.0f, une, acc);
    }
    __builtin_nontemporal_store(res, outp + (size_t)r * JG);
  }
}

extern "C" void kernel_launch(void* const* d_in, const int* in_sizes, int n_in,
                              void* d_out, int out_size, void* d_ws, size_t ws_size,
                              hipStream_t stream) {
  const float*  logits = (const float*)d_in[0];
  const float4* pred   = (const float4*)d_in[1];
  const int*    labels = (const int*)d_in[2];
  const float4* tboxes = (const float4*)d_in[3];
  vfloat4* out = (vfloat4*)d_out;

  dim3 grid(STRIPES, NQ / RCHUNK);             // (4, 1200) = 4800 blocks
  fused_kernel<<<grid, 256, 0, stream>>>(logits, pred, labels, tboxes, out);
}